// Round 7
// baseline (519.776 us; speedup 1.0000x reference)
//
#include <hip/hip_runtime.h>
#include <math.h>

#define B_ 16
#define N_ 288
#define C_ 32
#define H_ 32
#define BN_ (B_ * N_)       // 4608

#define K1_NT 2             // nodes per wave
#define K1_NODES 8          // nodes per block (4 waves)

#define TI 4                // i-rows per block in kernel 2
#define NTILES (N_ / TI)    // 72

typedef float v2f __attribute__((ext_vector_type(2)));

#define LAUNDER_S(p) asm volatile("" : "+s"(p))

// ---------------------------------------------------------------------------
// PROBE ROUND 2. Surfaced rep-loops with laundered blockIdx AND laundered
// source pointers (all "+s": stays in SGPR, scalar codegen preserved, but
// rep-invariant loads cannot be hoisted). All kernels idempotent.
// ---------------------------------------------------------------------------

// A: round-6 K1 (LDS-staged weights), + writes transposed pr layouts for C.
__global__ __launch_bounds__(256) void gru_proj_kernel(
    const float* __restrict__ inputs, const float* __restrict__ states,
    const float* __restrict__ rzW,    const float* __restrict__ rzb,
    const float* __restrict__ hcW,    const float* __restrict__ hcb,
    const float* __restrict__ c1W,    const float* __restrict__ c1b,
    const float* __restrict__ c2W,    const float* __restrict__ c2b,
    float* __restrict__ out_state,
    float* __restrict__ ps1, float* __restrict__ pr1,
    float* __restrict__ ps2, float* __restrict__ pr2,
    float* __restrict__ pr1T, float* __restrict__ pr2T, int reps)
{
    __shared__ __align__(16) float w_rz[64 * 64];
    __shared__ __align__(16) float w_hc[64 * 32];
    __shared__ __align__(16) float w_c1[64 * 32];
    __shared__ __align__(16) float w_c2[64 * 32];
    __shared__ __align__(16) float x_in[K1_NODES * 32];
    __shared__ __align__(16) float x_st[K1_NODES * 32];
    __shared__ __align__(16) float rs_a[4][K1_NT][32];

    const int tid = threadIdx.x;

    for (int rep = 0; rep < reps; ++rep) {
        int bx = blockIdx.x;
        asm volatile("" : "+s"(bx));
        const float* rzW_l = rzW;  LAUNDER_S(rzW_l);
        const float* hcW_l = hcW;  LAUNDER_S(hcW_l);
        const float* c1W_l = c1W;  LAUNDER_S(c1W_l);
        const float* c2W_l = c2W;  LAUNDER_S(c2W_l);
        const float* in_l  = inputs; LAUNDER_S(in_l);
        const float* st_l  = states; LAUNDER_S(st_l);

        __syncthreads();   // previous rep's LDS reads complete
        {
            const float4* s4 = (const float4*)rzW_l;
            float4* d4 = (float4*)w_rz;
            #pragma unroll
            for (int i = 0; i < 4; ++i) d4[tid + i * 256] = s4[tid + i * 256];
            const float4* sh = (const float4*)hcW_l;
            float4* dh = (float4*)w_hc;
            #pragma unroll
            for (int i = 0; i < 2; ++i) dh[tid + i * 256] = sh[tid + i * 256];
            const float4* sc = (const float4*)c1W_l;
            float4* dc = (float4*)w_c1;
            #pragma unroll
            for (int i = 0; i < 2; ++i) dc[tid + i * 256] = sc[tid + i * 256];
            #pragma unroll
            for (int i = 0; i < 8; ++i)
                w_c2[tid + i * 256] = c2W_l[tid + i * 256];
            const int nb = bx * K1_NODES * 32;
            x_in[tid] = in_l[nb + tid];
            x_st[tid] = st_l[nb + tid];
        }
        __syncthreads();

        const int w     = tid >> 6;
        const int lane  = tid & 63;
        const int o     = lane & 31;
        const int half  = lane >> 5;
        const int ln0   = w * K1_NT;
        const int node0 = bx * K1_NODES + ln0;

        float acc[K1_NT];
        const float rzbias = rzb[lane];
        acc[0] = rzbias; acc[1] = rzbias;

        #pragma unroll
        for (int q = 0; q < 8; ++q) {
            const float4 xa = *(const float4*)&x_in[(ln0 + 0) * 32 + q * 4];
            const float4 xb = *(const float4*)&x_in[(ln0 + 1) * 32 + q * 4];
            #pragma unroll
            for (int k4 = 0; k4 < 4; ++k4) {
                const float wk = w_rz[(q * 4 + k4) * 64 + lane];
                acc[0] = fmaf(((const float*)&xa)[k4], wk, acc[0]);
                acc[1] = fmaf(((const float*)&xb)[k4], wk, acc[1]);
            }
        }
        #pragma unroll
        for (int q = 0; q < 8; ++q) {
            const float4 xa = *(const float4*)&x_st[(ln0 + 0) * 32 + q * 4];
            const float4 xb = *(const float4*)&x_st[(ln0 + 1) * 32 + q * 4];
            #pragma unroll
            for (int k4 = 0; k4 < 4; ++k4) {
                const float wk = w_rz[(32 + q * 4 + k4) * 64 + lane];
                acc[0] = fmaf(((const float*)&xa)[k4], wk, acc[0]);
                acc[1] = fmaf(((const float*)&xb)[k4], wk, acc[1]);
            }
        }

        float z[K1_NT], st[K1_NT];
        #pragma unroll
        for (int t = 0; t < K1_NT; ++t) {
            const float rzv = 1.0f / (1.0f + __expf(-acc[t]));
            const float r   = __shfl(rzv, o);
            z[t]  = __shfl(rzv, o + 32);
            st[t] = x_st[(ln0 + t) * 32 + o];
            if (lane < 32) rs_a[w][t][o] = r * st[t];
        }

        const float* xs0 = half ? &rs_a[w][0][0] : &x_in[(ln0 + 0) * 32];
        const float* xs1 = half ? &rs_a[w][1][0] : &x_in[(ln0 + 1) * 32];
        float acc2[K1_NT] = {0.0f, 0.0f};
        #pragma unroll
        for (int q = 0; q < 8; ++q) {
            const float4 xa = *(const float4*)&xs0[q * 4];
            const float4 xb = *(const float4*)&xs1[q * 4];
            #pragma unroll
            for (int k4 = 0; k4 < 4; ++k4) {
                const float wk = w_hc[(half * 32 + q * 4 + k4) * 32 + o];
                acc2[0] = fmaf(((const float*)&xa)[k4], wk, acc2[0]);
                acc2[1] = fmaf(((const float*)&xb)[k4], wk, acc2[1]);
            }
        }

        const float hcbias = hcb[o];
        #pragma unroll
        for (int t = 0; t < K1_NT; ++t) {
            acc2[t] += __shfl_xor(acc2[t], 32);
            const float e  = __expf(2.0f * (acc2[t] + hcbias));
            const float hc = 1.0f - 2.0f / (e + 1.0f);
            const float ns = z[t] * st[t] + (1.0f - z[t]) * hc;
            if (lane < 32) out_state[(node0 + t) * H_ + o] = ns;
            if (lane < 32) rs_a[w][t][o] = fmaxf(ns, 0.0f);
        }

        float p1[K1_NT], p2[K1_NT];
        const float b1v = c1b[o], b2v = c2b[o];
        p1[0] = half ? 0.0f : b1v;  p1[1] = p1[0];
        p2[0] = half ? 0.0f : b2v;  p2[1] = p2[0];
        #pragma unroll
        for (int q = 0; q < 8; ++q) {
            const float4 aa = *(const float4*)&rs_a[w][0][q * 4];
            const float4 ab = *(const float4*)&rs_a[w][1][q * 4];
            #pragma unroll
            for (int k4 = 0; k4 < 4; ++k4) {
                const int row  = half * 32 + q * 4 + k4;
                const float w1 = w_c1[row * 32 + o];
                const float w2 = w_c2[row * 32 + o];
                const float a0 = ((const float*)&aa)[k4];
                const float a1 = ((const float*)&ab)[k4];
                p1[0] = fmaf(a0, w1, p1[0]);
                p1[1] = fmaf(a1, w1, p1[1]);
                p2[0] = fmaf(a0, w2, p2[0]);
                p2[1] = fmaf(a1, w2, p2[1]);
            }
        }
        float* d1 = half ? pr1 : ps1;
        float* d2 = half ? pr2 : ps2;
        #pragma unroll
        for (int t = 0; t < K1_NT; ++t) {
            d1[(node0 + t) * H_ + o] = p1[t];
            d2[(node0 + t) * H_ + o] = p2[t];
            if (half) {   // transposed layout for probe C
                const int q = o >> 2, rr = o & 3;
                pr1T[((size_t)q * BN_ + node0 + t) * 4 + rr] = p1[t];
                pr2T[((size_t)q * BN_ + node0 + t) * 4 + rr] = p2[t];
            }
        }
    }
}

// B: round-6 pair kernel (pk math, LDS-staged ps, strided pr loads).
__global__ __launch_bounds__(320) void pair_r6_kernel(
    const float* __restrict__ ps1, const float* __restrict__ pr1,
    const float* __restrict__ ps2, const float* __restrict__ pr2,
    const float* __restrict__ w1g, const float* __restrict__ b1g,
    const float* __restrict__ w2g, const float* __restrict__ b2g,
    float* __restrict__ out, int reps)
{
    const int tid = threadIdx.x;
    __shared__ __align__(16) float s1[TI * 32];
    __shared__ __align__(16) float s2[TI * 32];

    for (int rep = 0; rep < reps; ++rep) {
        int bx = blockIdx.x;
        asm volatile("" : "+s"(bx));
        const float* ps1_l = ps1; LAUNDER_S(ps1_l);
        const float* ps2_l = ps2; LAUNDER_S(ps2_l);
        const float* pr1_l = pr1; LAUNDER_S(pr1_l);
        const float* pr2_l = pr2; LAUNDER_S(pr2_l);
        const int b  = bx / NTILES;
        const int i0 = (bx % NTILES) * TI;

        __syncthreads();
        const size_t rowbase = (size_t)(b * N_ + i0) * H_;
        if (tid < TI * 32)            s1[tid]           = ps1_l[rowbase + tid];
        else if (tid < 2 * TI * 32)   s2[tid - TI * 32] = ps2_l[rowbase + (tid - TI * 32)];
        __syncthreads();

        const int j = tid;
        if (j < N_) {
            const v2f zero = {0.0f, 0.0f};
            float acc1[TI];
            {
                const float4* prp = (const float4*)(pr1_l + (size_t)(b * N_ + j) * H_);
                v2f p0[8], p1v[8], w0[8], w1v[8];
                #pragma unroll
                for (int c = 0; c < 8; ++c) {
                    const float4 pv = prp[c];
                    p0[c]  = (v2f){pv.x, pv.y};
                    p1v[c] = (v2f){pv.z, pv.w};
                    w0[c]  = (v2f){w1g[4 * c + 0], w1g[4 * c + 1]};
                    w1v[c] = (v2f){w1g[4 * c + 2], w1g[4 * c + 3]};
                }
                const float b1 = b1g[0];
                #pragma unroll
                for (int ii = 0; ii < TI; ++ii) {
                    v2f aA = {b1, 0.0f}, aB = zero;
                    #pragma unroll
                    for (int c = 0; c < 8; ++c) {
                        const float4 sv = *(const float4*)&s1[ii * 32 + c * 4];
                        v2f u0 = (v2f){sv.x, sv.y} + p0[c];
                        v2f u1 = (v2f){sv.z, sv.w} + p1v[c];
                        u0 = __builtin_elementwise_max(u0, zero);
                        u1 = __builtin_elementwise_max(u1, zero);
                        aA = u0 * w0[c] + aA;
                        aB = u1 * w1v[c] + aB;
                    }
                    acc1[ii] = aA.x + aA.y + aB.x + aB.y;
                }
            }
            {
                const float4* prp = (const float4*)(pr2_l + (size_t)(b * N_ + j) * H_);
                v2f p0[8], p1v[8], w0[8], w1v[8];
                #pragma unroll
                for (int c = 0; c < 8; ++c) {
                    const float4 pv = prp[c];
                    p0[c]  = (v2f){pv.x, pv.y};
                    p1v[c] = (v2f){pv.z, pv.w};
                    w0[c]  = (v2f){w2g[4 * c + 0], w2g[4 * c + 1]};
                    w1v[c] = (v2f){w2g[4 * c + 2], w2g[4 * c + 3]};
                }
                const float b2 = b2g[0];
                float* orow = out + (size_t)(b * N_ + i0) * N_ + j;
                #pragma unroll
                for (int ii = 0; ii < TI; ++ii) {
                    v2f aA = {b2, 0.0f}, aB = zero;
                    #pragma unroll
                    for (int c = 0; c < 8; ++c) {
                        const float4 sv = *(const float4*)&s2[ii * 32 + c * 4];
                        v2f u0 = (v2f){sv.x, sv.y} + p0[c];
                        v2f u1 = (v2f){sv.z, sv.w} + p1v[c];
                        u0 = __builtin_elementwise_max(u0, zero);
                        u1 = __builtin_elementwise_max(u1, zero);
                        aA = u0 * w0[c] + aA;
                        aB = u1 * w1v[c] + aB;
                    }
                    const float m   = aA.x + aA.y + aB.x + aB.y;
                    const float sig = 1.0f / (1.0f + __expf(-m));
                    orow[(size_t)ii * N_] = acc1[ii] * sig;
                }
            }
        }
    }
}

// C: same as B but pr read from transposed layout -> coalesced float4 loads.
__global__ __launch_bounds__(320) void pair_T_kernel(
    const float* __restrict__ ps1, const float* __restrict__ pr1T,
    const float* __restrict__ ps2, const float* __restrict__ pr2T,
    const float* __restrict__ w1g, const float* __restrict__ b1g,
    const float* __restrict__ w2g, const float* __restrict__ b2g,
    float* __restrict__ out, int reps)
{
    const int tid = threadIdx.x;
    __shared__ __align__(16) float s1[TI * 32];
    __shared__ __align__(16) float s2[TI * 32];

    for (int rep = 0; rep < reps; ++rep) {
        int bx = blockIdx.x;
        asm volatile("" : "+s"(bx));
        const float* ps1_l = ps1;  LAUNDER_S(ps1_l);
        const float* ps2_l = ps2;  LAUNDER_S(ps2_l);
        const float* pr1_l = pr1T; LAUNDER_S(pr1_l);
        const float* pr2_l = pr2T; LAUNDER_S(pr2_l);
        const int b  = bx / NTILES;
        const int i0 = (bx % NTILES) * TI;

        __syncthreads();
        const size_t rowbase = (size_t)(b * N_ + i0) * H_;
        if (tid < TI * 32)            s1[tid]           = ps1_l[rowbase + tid];
        else if (tid < 2 * TI * 32)   s2[tid - TI * 32] = ps2_l[rowbase + (tid - TI * 32)];
        __syncthreads();

        const int j = tid;
        if (j < N_) {
            const size_t jj = (size_t)(b * N_ + j);
            const v2f zero = {0.0f, 0.0f};
            float acc1[TI];
            {
                const float4* prp = (const float4*)pr1_l;   // [q*BN_+node]
                v2f p0[8], p1v[8], w0[8], w1v[8];
                #pragma unroll
                for (int c = 0; c < 8; ++c) {
                    const float4 pv = prp[(size_t)c * BN_ + jj];  // coalesced
                    p0[c]  = (v2f){pv.x, pv.y};
                    p1v[c] = (v2f){pv.z, pv.w};
                    w0[c]  = (v2f){w1g[4 * c + 0], w1g[4 * c + 1]};
                    w1v[c] = (v2f){w1g[4 * c + 2], w1g[4 * c + 3]};
                }
                const float b1 = b1g[0];
                #pragma unroll
                for (int ii = 0; ii < TI; ++ii) {
                    v2f aA = {b1, 0.0f}, aB = zero;
                    #pragma unroll
                    for (int c = 0; c < 8; ++c) {
                        const float4 sv = *(const float4*)&s1[ii * 32 + c * 4];
                        v2f u0 = (v2f){sv.x, sv.y} + p0[c];
                        v2f u1 = (v2f){sv.z, sv.w} + p1v[c];
                        u0 = __builtin_elementwise_max(u0, zero);
                        u1 = __builtin_elementwise_max(u1, zero);
                        aA = u0 * w0[c] + aA;
                        aB = u1 * w1v[c] + aB;
                    }
                    acc1[ii] = aA.x + aA.y + aB.x + aB.y;
                }
            }
            {
                const float4* prp = (const float4*)pr2_l;
                v2f p0[8], p1v[8], w0[8], w1v[8];
                #pragma unroll
                for (int c = 0; c < 8; ++c) {
                    const float4 pv = prp[(size_t)c * BN_ + jj];
                    p0[c]  = (v2f){pv.x, pv.y};
                    p1v[c] = (v2f){pv.z, pv.w};
                    w0[c]  = (v2f){w2g[4 * c + 0], w2g[4 * c + 1]};
                    w1v[c] = (v2f){w2g[4 * c + 2], w2g[4 * c + 3]};
                }
                const float b2 = b2g[0];
                float* orow = out + (size_t)(b * N_ + i0) * N_ + j;
                #pragma unroll
                for (int ii = 0; ii < TI; ++ii) {
                    v2f aA = {b2, 0.0f}, aB = zero;
                    #pragma unroll
                    for (int c = 0; c < 8; ++c) {
                        const float4 sv = *(const float4*)&s2[ii * 32 + c * 4];
                        v2f u0 = (v2f){sv.x, sv.y} + p0[c];
                        v2f u1 = (v2f){sv.z, sv.w} + p1v[c];
                        u0 = __builtin_elementwise_max(u0, zero);
                        u1 = __builtin_elementwise_max(u1, zero);
                        aA = u0 * w0[c] + aA;
                        aB = u1 * w1v[c] + aB;
                    }
                    const float m   = aA.x + aA.y + aB.x + aB.y;
                    const float sig = 1.0f / (1.0f + __expf(-m));
                    orow[(size_t)ii * N_] = acc1[ii] * sig;
                }
            }
        }
    }
}

extern "C" void kernel_launch(void* const* d_in, const int* in_sizes, int n_in,
                              void* d_out, int out_size, void* d_ws, size_t ws_size,
                              hipStream_t stream) {
    const float* inputs = (const float*)d_in[0];
    const float* states = (const float*)d_in[1];
    const float* rzW    = (const float*)d_in[2];
    const float* rzb    = (const float*)d_in[3];
    const float* hcW    = (const float*)d_in[4];
    const float* hcb    = (const float*)d_in[5];
    const float* c1W    = (const float*)d_in[6];
    const float* c1b    = (const float*)d_in[7];
    const float* c1w1   = (const float*)d_in[8];
    const float* c1b1   = (const float*)d_in[9];
    const float* c2W    = (const float*)d_in[10];
    const float* c2b    = (const float*)d_in[11];
    const float* c2w1   = (const float*)d_in[12];
    const float* c2b1   = (const float*)d_in[13];

    float* out_support = (float*)d_out;
    float* out_state   = out_support + (size_t)BN_ * N_;

    float* ws   = (float*)d_ws;
    float* ps1  = ws;
    float* pr1  = ws + 1 * (size_t)BN_ * H_;
    float* ps2  = ws + 2 * (size_t)BN_ * H_;
    float* pr2  = ws + 3 * (size_t)BN_ * H_;
    float* pr1T = ws + 4 * (size_t)BN_ * H_;
    float* pr2T = ws + 5 * (size_t)BN_ * H_;

    gru_proj_kernel<<<BN_ / K1_NODES, 256, 0, stream>>>(
        inputs, states, rzW, rzb, hcW, hcb, c1W, c1b, c2W, c2b,
        out_state, ps1, pr1, ps2, pr2, pr1T, pr2T, 20);

    pair_r6_kernel<<<B_ * NTILES, 320, 0, stream>>>(
        ps1, pr1, ps2, pr2, c1w1, c1b1, c2w1, c2b1, out_support, 12);

    pair_T_kernel<<<B_ * NTILES, 320, 0, stream>>>(
        ps1, pr1T, ps2, pr2T, c1w1, c1b1, c2w1, c2b1, out_support, 14);
}

// Round 8
// 28.002 us; speedup vs baseline: 18.5618x; 18.5618x over previous
//
#include <hip/hip_runtime.h>
#include <math.h>

#define B_ 16
#define N_ 288
#define C_ 32
#define H_ 32
#define BN_ (B_ * N_)       // 4608
#define NT 4                // nodes per wave in kernel 1

#define TI 4                // i-rows per block in kernel 2
#define NTILES (N_ / TI)    // 72

typedef float v2f __attribute__((ext_vector_type(2)));

// ---------------------------------------------------------------------------
// Kernel 1: GRU cell + projections. Round-2 structure (NT=4 nodes/wave, one
// wave/block, weights streamed via L1 -- NO bulk LDS staging, which probe r7
// showed costs 11.5us/rep). Upgrades: rz matvec split into 8 independent FMA
// chains (inputs-half + states-half) for ILP; x fetched as uniform float4
// (s_load_dwordx4); receiver projections written TRANSPOSED (prT[q][node][4])
// so kernel 2's pr loads are lane-coalesced.
// ---------------------------------------------------------------------------
__global__ __launch_bounds__(64) void gru_proj_kernel(
    const float* __restrict__ inputs, const float* __restrict__ states,
    const float* __restrict__ rzW,    const float* __restrict__ rzb,
    const float* __restrict__ hcW,    const float* __restrict__ hcb,
    const float* __restrict__ c1W,    const float* __restrict__ c1b,
    const float* __restrict__ c2W,    const float* __restrict__ c2b,
    float* __restrict__ out_state,
    float* __restrict__ ps1, float* __restrict__ ps2,
    float* __restrict__ pr1T, float* __restrict__ pr2T)
{
    const int lane  = threadIdx.x;
    const int o     = lane & 31;
    const int half  = lane >> 5;
    const int node0 = blockIdx.x * NT;

    __shared__ __align__(16) float xh_sh[NT][64];  // [0:32)=inputs, [32:64)=r*state
    __shared__ __align__(16) float a_sh[NT][32];   // relu(new_state)

    // stage inputs half for the hc phase (lanes 0..31, coalesced v_load)
    if (!half) {
        #pragma unroll
        for (int t = 0; t < NT; ++t)
            xh_sh[t][o] = inputs[(node0 + t) * C_ + o];
    }

    // ---- r_z: 8 independent chains (4 nodes x {inputs,states} halves) ----
    float acc_i[NT], acc_s[NT];
    const float rzbias = rzb[lane];
    #pragma unroll
    for (int t = 0; t < NT; ++t) { acc_i[t] = rzbias; acc_s[t] = 0.0f; }

    #pragma unroll
    for (int q = 0; q < 8; ++q) {
        float4 xi[NT], xs[NT];
        #pragma unroll
        for (int t = 0; t < NT; ++t) {          // wave-uniform -> s_load_dwordx4
            xi[t] = *(const float4*)&inputs[(node0 + t) * C_ + q * 4];
            xs[t] = *(const float4*)&states[(node0 + t) * H_ + q * 4];
        }
        #pragma unroll
        for (int k4 = 0; k4 < 4; ++k4) {
            const float wi = rzW[(q * 4 + k4) * 64 + lane];
            const float ws = rzW[(32 + q * 4 + k4) * 64 + lane];
            #pragma unroll
            for (int t = 0; t < NT; ++t) {
                acc_i[t] = fmaf(((const float*)&xi[t])[k4], wi, acc_i[t]);
                acc_s[t] = fmaf(((const float*)&xs[t])[k4], ws, acc_s[t]);
            }
        }
    }

    float z[NT], st[NT];
    #pragma unroll
    for (int t = 0; t < NT; ++t) {
        const float rzv = 1.0f / (1.0f + __expf(-(acc_i[t] + acc_s[t])));
        const float r   = __shfl(rzv, o);        // r[o] to both halves
        z[t]  = __shfl(rzv, o + 32);             // z[o] to both halves
        st[t] = states[(node0 + t) * H_ + o];
        if (half) xh_sh[t][32 + o] = r * st[t];
    }
    __syncthreads();   // 1-wave block: near-free, orders ds_write->ds_read

    // ---- h_cand: split-K across halves (half0: inputs, half1: r*state) ----
    float acc2[NT] = {0.0f, 0.0f, 0.0f, 0.0f};
    #pragma unroll
    for (int q = 0; q < 8; ++q) {
        float4 xh[NT];
        #pragma unroll
        for (int t = 0; t < NT; ++t)
            xh[t] = *(const float4*)&xh_sh[t][half * 32 + q * 4];  // 2-addr broadcast
        #pragma unroll
        for (int k4 = 0; k4 < 4; ++k4) {
            const float wk = hcW[(half * 32 + q * 4 + k4) * 32 + o];
            #pragma unroll
            for (int t = 0; t < NT; ++t)
                acc2[t] = fmaf(((const float*)&xh[t])[k4], wk, acc2[t]);
        }
    }

    const float hcbias = hcb[o];
    #pragma unroll
    for (int t = 0; t < NT; ++t) {
        acc2[t] += __shfl_xor(acc2[t], 32);      // merge k-halves
        // tanh(x) = 1 - 2/(exp(2x)+1)
        const float e  = __expf(2.0f * (acc2[t] + hcbias));
        const float hc = 1.0f - 2.0f / (e + 1.0f);
        const float ns = z[t] * st[t] + (1.0f - z[t]) * hc;
        if (!half) {
            out_state[(node0 + t) * H_ + o] = ns;
            a_sh[t][o] = fmaxf(ns, 0.0f);
        }
    }
    __syncthreads();

    // ---- projections: lane = [sender unit | receiver unit] ----
    float p1[NT], p2[NT];
    const float b1v = c1b[o], b2v = c2b[o];
    #pragma unroll
    for (int t = 0; t < NT; ++t) {
        p1[t] = half ? 0.0f : b1v;               // fc2 bias folded into sender
        p2[t] = half ? 0.0f : b2v;
    }
    const int rb = half * 32;
    #pragma unroll
    for (int q = 0; q < 8; ++q) {
        float4 aq[NT];
        #pragma unroll
        for (int t = 0; t < NT; ++t)
            aq[t] = *(const float4*)&a_sh[t][q * 4];   // b128 broadcast
        #pragma unroll
        for (int k4 = 0; k4 < 4; ++k4) {
            const int row  = rb + q * 4 + k4;
            const float w1 = c1W[row * 32 + o];
            const float w2 = c2W[row * 32 + o];
            #pragma unroll
            for (int t = 0; t < NT; ++t) {
                const float av = ((const float*)&aq[t])[k4];
                p1[t] = fmaf(av, w1, p1[t]);
                p2[t] = fmaf(av, w2, p2[t]);
            }
        }
    }
    if (!half) {
        #pragma unroll
        for (int t = 0; t < NT; ++t) {
            ps1[(node0 + t) * H_ + o] = p1[t];
            ps2[(node0 + t) * H_ + o] = p2[t];
        }
    } else {
        const int qo = o >> 2, ro = o & 3;       // transposed receiver layout
        #pragma unroll
        for (int t = 0; t < NT; ++t) {
            pr1T[((size_t)qo * BN_ + node0 + t) * 4 + ro] = p1[t];
            pr2T[((size_t)qo * BN_ + node0 + t) * 4 + ro] = p2[t];
        }
    }
}

// ---------------------------------------------------------------------------
// Kernel 2: pair conv (probe-C winner). ps rows LDS-staged (broadcast b128
// reads); pr read COALESCED from transposed layout float4[q][node]; packed-f32
// inner loop. 1152 blocks x 320 threads.
// ---------------------------------------------------------------------------
__global__ __launch_bounds__(320) void pair_kernel(
    const float* __restrict__ ps1, const float* __restrict__ pr1T,
    const float* __restrict__ ps2, const float* __restrict__ pr2T,
    const float* __restrict__ w1g, const float* __restrict__ b1g,
    const float* __restrict__ w2g, const float* __restrict__ b2g,
    float* __restrict__ out)
{
    const int tid = threadIdx.x;
    const int b   = blockIdx.x / NTILES;
    const int i0  = (blockIdx.x % NTILES) * TI;

    __shared__ __align__(16) float s1[TI * 32];
    __shared__ __align__(16) float s2[TI * 32];

    const size_t rowbase = (size_t)(b * N_ + i0) * H_;
    if (tid < TI * 32)            s1[tid]           = ps1[rowbase + tid];
    else if (tid < 2 * TI * 32)   s2[tid - TI * 32] = ps2[rowbase + (tid - TI * 32)];
    __syncthreads();

    const int j = tid;
    if (j < N_) {
        const size_t jj = (size_t)(b * N_ + j);
        const v2f zero = {0.0f, 0.0f};
        float acc1[TI];

        // ---- conv1 (support) ----
        {
            const float4* prp = (const float4*)pr1T;
            v2f p0[8], p1v[8], w0[8], w1v[8];
            #pragma unroll
            for (int c = 0; c < 8; ++c) {
                const float4 pv = prp[(size_t)c * BN_ + jj];   // coalesced
                p0[c]  = (v2f){pv.x, pv.y};
                p1v[c] = (v2f){pv.z, pv.w};
                w0[c]  = (v2f){w1g[4 * c + 0], w1g[4 * c + 1]};
                w1v[c] = (v2f){w1g[4 * c + 2], w1g[4 * c + 3]};
            }
            const float b1 = b1g[0];
            #pragma unroll
            for (int ii = 0; ii < TI; ++ii) {
                v2f aA = {b1, 0.0f}, aB = zero;
                #pragma unroll
                for (int c = 0; c < 8; ++c) {
                    const float4 sv = *(const float4*)&s1[ii * 32 + c * 4];
                    v2f u0 = (v2f){sv.x, sv.y} + p0[c];
                    v2f u1 = (v2f){sv.z, sv.w} + p1v[c];
                    u0 = __builtin_elementwise_max(u0, zero);
                    u1 = __builtin_elementwise_max(u1, zero);
                    aA = u0 * w0[c] + aA;      // v_pk_fma_f32
                    aB = u1 * w1v[c] + aB;
                }
                acc1[ii] = aA.x + aA.y + aB.x + aB.y;
            }
        }

        // ---- conv2 (mask) + epilogue ----
        {
            const float4* prp = (const float4*)pr2T;
            v2f p0[8], p1v[8], w0[8], w1v[8];
            #pragma unroll
            for (int c = 0; c < 8; ++c) {
                const float4 pv = prp[(size_t)c * BN_ + jj];
                p0[c]  = (v2f){pv.x, pv.y};
                p1v[c] = (v2f){pv.z, pv.w};
                w0[c]  = (v2f){w2g[4 * c + 0], w2g[4 * c + 1]};
                w1v[c] = (v2f){w2g[4 * c + 2], w2g[4 * c + 3]};
            }
            const float b2 = b2g[0];
            float* orow = out + (size_t)(b * N_ + i0) * N_ + j;
            #pragma unroll
            for (int ii = 0; ii < TI; ++ii) {
                v2f aA = {b2, 0.0f}, aB = zero;
                #pragma unroll
                for (int c = 0; c < 8; ++c) {
                    const float4 sv = *(const float4*)&s2[ii * 32 + c * 4];
                    v2f u0 = (v2f){sv.x, sv.y} + p0[c];
                    v2f u1 = (v2f){sv.z, sv.w} + p1v[c];
                    u0 = __builtin_elementwise_max(u0, zero);
                    u1 = __builtin_elementwise_max(u1, zero);
                    aA = u0 * w0[c] + aA;
                    aB = u1 * w1v[c] + aB;
                }
                const float m   = aA.x + aA.y + aB.x + aB.y;
                const float sig = 1.0f / (1.0f + __expf(-m));
                orow[(size_t)ii * N_] = acc1[ii] * sig;
            }
        }
    }
}

extern "C" void kernel_launch(void* const* d_in, const int* in_sizes, int n_in,
                              void* d_out, int out_size, void* d_ws, size_t ws_size,
                              hipStream_t stream) {
    const float* inputs = (const float*)d_in[0];
    const float* states = (const float*)d_in[1];
    const float* rzW    = (const float*)d_in[2];
    const float* rzb    = (const float*)d_in[3];
    const float* hcW    = (const float*)d_in[4];
    const float* hcb    = (const float*)d_in[5];
    const float* c1W    = (const float*)d_in[6];
    const float* c1b    = (const float*)d_in[7];
    const float* c1w1   = (const float*)d_in[8];
    const float* c1b1   = (const float*)d_in[9];
    const float* c2W    = (const float*)d_in[10];
    const float* c2b    = (const float*)d_in[11];
    const float* c2w1   = (const float*)d_in[12];
    const float* c2b1   = (const float*)d_in[13];

    float* out_support = (float*)d_out;
    float* out_state   = out_support + (size_t)BN_ * N_;

    float* ws   = (float*)d_ws;
    float* ps1  = ws;
    float* ps2  = ws + 1 * (size_t)BN_ * H_;
    float* pr1T = ws + 2 * (size_t)BN_ * H_;
    float* pr2T = ws + 3 * (size_t)BN_ * H_;

    gru_proj_kernel<<<BN_ / NT, 64, 0, stream>>>(
        inputs, states, rzW, rzb, hcW, hcb, c1W, c1b, c2W, c2b,
        out_state, ps1, ps2, pr1T, pr2T);

    pair_kernel<<<B_ * NTILES, 320, 0, stream>>>(
        ps1, pr1T, ps2, pr2T, c1w1, c1b1, c2w1, c2b1, out_support);
}